// Round 17
// baseline (4940.590 us; speedup 1.0000x reference)
//
#include <hip/hip_runtime.h>
#include <hip/hip_bf16.h>

// Problem constants (match reference).
#define VOCAB  50257
#define D_EMB  128
#define HID    256
#define N_CLS  2
#define BSZ    256
#define T_LEN  2048
#define G      16          // batch rows per block (MFMA M dim)
#define NBLK   (BSZ / G)   // 16 blocks
#define RSTR   264         // LDS row stride in shorts (16B-aligned: 528 B)

typedef __attribute__((ext_vector_type(8))) short s8v;   // 8 bf16 (4 VGPR)
typedef __attribute__((ext_vector_type(4))) float f4v;   // 4 f32  (4 VGPR)

// ---------------------------------------------------------------------------
// Kernel 1: tab[v][j] = sum_d emb_table[v][d] * wx_w[d][j] + wx_b[j] + wh_b[j]
// ---------------------------------------------------------------------------
__global__ __launch_bounds__(256)
void tabax_kernel(const float* __restrict__ emb,
                  const float* __restrict__ wxw,
                  const float* __restrict__ wxb,
                  const float* __restrict__ whb,
                  float* __restrict__ tab)
{
    const int j  = threadIdx.x;
    const int v0 = blockIdx.x * 32;
    const int rows = min(32, VOCAB - v0);

    __shared__ float ebuf[32 * D_EMB];
    for (int i = j; i < rows * D_EMB; i += 256)
        ebuf[i] = emb[(size_t)v0 * D_EMB + i];
    __syncthreads();

    float acc[32];
#pragma unroll
    for (int r = 0; r < 32; ++r) acc[r] = 0.f;

#pragma unroll 8
    for (int d = 0; d < D_EMB; ++d) {
        float wxv = wxw[d * HID + j];
#pragma unroll
        for (int r = 0; r < 32; ++r)
            acc[r] = fmaf(ebuf[r * D_EMB + d], wxv, acc[r]);
    }

    const float bb = wxb[j] + whb[j];
    for (int r = 0; r < rows; ++r)
        tab[(size_t)(v0 + r) * HID + j] = acc[r] + bb;
}

__device__ __forceinline__ float fast_tanh(float x) {
    float e2 = __expf(2.f * x);
    return 1.f - 2.f / (e2 + 1.f);
}

// f32 = bf16 hi + bf16 lo (truncating split); 3-product MFMA scheme drops
// only the lo*lo term (~8e-6/step). Verified e2e in R13 (absmax 1.2e-4).
__device__ __forceinline__ void split_bf16(float x, unsigned short& hi,
                                           unsigned short& lo) {
    unsigned int u = __float_as_uint(x);
    hi = (unsigned short)(u >> 16);
    float hif = __uint_as_float(u & 0xFFFF0000u);
    float r = x - hif;
    lo = (unsigned short)(__float_as_uint(r) >> 16);
}
__device__ __forceinline__ float bf2f(unsigned short h) {
    return __uint_as_float(((unsigned int)h) << 16);
}

// ---------------------------------------------------------------------------
// Kernel 2 (main): 16 blocks x 256 threads (4 waves). Block g owns batch
// rows [g*16, g*16+16). The recurrent update for ALL 16 rows runs as real
// 16x16x32 bf16 MFMAs with ZERO row duplication (R13's 16x-redundant
// broadcast removed):
//   A = h[16 rows][256 k] in LDS (bf16 hi/lo, row stride 264 shorts);
//       lane l reads A[l&15][(l>>4)*8 + s*32 ..+8] -- per-lane base +
//       immediate s*64 offsets (k-map e2e-verified by R13's pass).
//   B = Whh split hi/lo in registers: wave w covers cols [w*64, w*64+64)
//       as 4 col-tiles; 4x8x2 = 64 frags = 256 regs/lane. RA may home them
//       in AGPRs -- MFMA reads AGPRs natively, so the 15-round copy tax
//       is structurally gone.
//   C (m89-verified: col=lane&15, row=(lane>>4)*4+reg): lane finalizes 16
//       (row,col) cells: x = c1+c2+c3 + ax[tok[row]][col]; tanh; split;
//       2 ds_write_b16 -> next h buffer. One barrier per step.
// Per step/wave: 96 MFMA (MFMA pipe) || 16 ds_read_b128 (DS pipe) || ~200
// VALU -- pipes overlap (m114).
// ---------------------------------------------------------------------------
__global__ __launch_bounds__(256, 1)
void rnn_mfma_kernel(const int*   __restrict__ batch,
                     const float* __restrict__ whw,
                     const float* __restrict__ clfw,
                     const float* __restrict__ clfb,
                     const float* __restrict__ ax_tab,
                     float*       __restrict__ out)
{
    const int g    = blockIdx.x;
    const int tid  = threadIdx.x;
    const int wave = tid >> 6;           // 0..3: cols [wave*64, wave*64+64)
    const int lane = tid & 63;
    const int lq   = lane >> 4;          // k-chunk / row-group selector
    const int lc   = lane & 15;          // col-in-tile / A-row selector

    // [buf][hi=0,lo=1][row*RSTR + k]
    __shared__ unsigned short hsh[2][2][G * RSTR];

    // --- one-time B-fragment build (k = s*32 + lq*8 + j, col per tile) ---
    s8v bhi[4][8], blo[4][8];
#pragma unroll
    for (int ti = 0; ti < 4; ++ti)
#pragma unroll
        for (int s = 0; s < 8; ++s)
#pragma unroll
            for (int j = 0; j < 8; ++j) {
                const int k   = s * 32 + lq * 8 + j;
                const int col = wave * 64 + ti * 16 + lc;
                unsigned short hi, lo;
                split_bf16(whw[(size_t)k * HID + col], hi, lo);
                bhi[ti][s][j] = (short)hi;
                blo[ti][s][j] = (short)lo;
            }

    // token stream base pointers for the 4 rows this lane finalizes
    const int r0 = lq * 4;
    const int* bp[4];
#pragma unroll
    for (int reg = 0; reg < 4; ++reg)
        bp[reg] = batch + (size_t)(g * G + r0 + reg) * T_LEN;

    // zero h(t=0)
    for (int i = tid; i < G * RSTR; i += 256) {
        hsh[0][0][i] = 0; hsh[0][1][i] = 0;
    }

    int tokn[4];
    float axv[4][4];                     // [ti][reg]
#pragma unroll
    for (int reg = 0; reg < 4; ++reg) tokn[reg] = bp[reg][0];
#pragma unroll
    for (int ti = 0; ti < 4; ++ti)
#pragma unroll
        for (int reg = 0; reg < 4; ++reg)
            axv[ti][reg] = ax_tab[(size_t)(unsigned)tokn[reg] * HID +
                                  wave * 64 + ti * 16 + lc];
#pragma unroll
    for (int reg = 0; reg < 4; ++reg) tokn[reg] = bp[reg][1];
    __syncthreads();

    const int abase = lc * RSTR + lq * 8;            // A-frag (shorts)
    const int wbase = r0 * RSTR + wave * 64 + lc;    // h-write (shorts)

#define STEP(CUR, NXT, TT)                                                  \
    {                                                                       \
        int toknn[4];                                                       \
        _Pragma("unroll")                                                   \
        for (int reg = 0; reg < 4; ++reg)                                   \
            toknn[reg] = ((TT) + 2 < T_LEN) ? bp[reg][(TT) + 2] : 0;        \
        float axn[4][4];                                                    \
        _Pragma("unroll")                                                   \
        for (int ti = 0; ti < 4; ++ti)                                      \
            _Pragma("unroll")                                               \
            for (int reg = 0; reg < 4; ++reg)                               \
                axn[ti][reg] = ax_tab[(size_t)(unsigned)tokn[reg] * HID +   \
                                      wave * 64 + ti * 16 + lc];            \
        f4v c1[4], c2[4], c3[4];                                            \
        _Pragma("unroll")                                                   \
        for (int ti = 0; ti < 4; ++ti) {                                    \
            c1[ti] = (f4v){0.f, 0.f, 0.f, 0.f};                             \
            c2[ti] = (f4v){0.f, 0.f, 0.f, 0.f};                             \
            c3[ti] = (f4v){0.f, 0.f, 0.f, 0.f};                             \
        }                                                                   \
        const unsigned short* Hh = &hsh[CUR][0][0];                         \
        const unsigned short* Hl = &hsh[CUR][1][0];                         \
        _Pragma("unroll")                                                   \
        for (int s = 0; s < 8; ++s) {                                       \
            const s8v ah = *(const s8v*)&Hh[abase + s * 32];                \
            const s8v al = *(const s8v*)&Hl[abase + s * 32];                \
            _Pragma("unroll")                                               \
            for (int ti = 0; ti < 4; ++ti) {                                \
                c1[ti] = __builtin_amdgcn_mfma_f32_16x16x32_bf16(           \
                             ah, bhi[ti][s], c1[ti], 0, 0, 0);              \
                c2[ti] = __builtin_amdgcn_mfma_f32_16x16x32_bf16(           \
                             ah, blo[ti][s], c2[ti], 0, 0, 0);              \
                c3[ti] = __builtin_amdgcn_mfma_f32_16x16x32_bf16(           \
                             al, bhi[ti][s], c3[ti], 0, 0, 0);              \
            }                                                               \
        }                                                                   \
        unsigned short* Wh = &hsh[NXT][0][0];                               \
        unsigned short* Wl = &hsh[NXT][1][0];                               \
        _Pragma("unroll")                                                   \
        for (int ti = 0; ti < 4; ++ti)                                      \
            _Pragma("unroll")                                               \
            for (int reg = 0; reg < 4; ++reg) {                             \
                const float x = (c1[ti][reg] + c2[ti][reg]) + c3[ti][reg] + \
                                axv[ti][reg];                               \
                const float hn = fast_tanh(x);                              \
                unsigned short hi_, lo_;                                    \
                split_bf16(hn, hi_, lo_);                                   \
                Wh[wbase + ti * 16 + reg * RSTR] = hi_;                     \
                Wl[wbase + ti * 16 + reg * RSTR] = lo_;                     \
            }                                                               \
        __syncthreads();                                                    \
        _Pragma("unroll")                                                   \
        for (int ti = 0; ti < 4; ++ti)                                      \
            _Pragma("unroll")                                               \
            for (int reg = 0; reg < 4; ++reg) axv[ti][reg] = axn[ti][reg];  \
        _Pragma("unroll")                                                   \
        for (int reg = 0; reg < 4; ++reg) tokn[reg] = toknn[reg];           \
    }

    for (int t = 0; t < T_LEN; t += 2) {
        STEP(0, 1, t)
        STEP(1, 0, t + 1)
    }
#undef STEP

    // --- epilogue: out[g*16+r][c] = sum_j h[r][j] * clf_w[j][c] + clf_b[c]
    // (final h in buf 0 after an even number of steps)
    {
        const unsigned short* Fh = &hsh[0][0][0];
        const unsigned short* Fl = &hsh[0][1][0];
        const int r  = tid >> 4;         // row 0..15
        const int jg = tid & 15;         // j-chunk
        float p0 = 0.f, p1 = 0.f;
#pragma unroll
        for (int jj = 0; jj < 16; ++jj) {
            const int j = jg * 16 + jj;
            const float h = bf2f(Fh[r * RSTR + j]) + bf2f(Fl[r * RSTR + j]);
            p0 = fmaf(h, clfw[j * N_CLS + 0], p0);
            p1 = fmaf(h, clfw[j * N_CLS + 1], p1);
        }
#pragma unroll
        for (int m = 1; m <= 8; m <<= 1) {   // reduce within 16-lane group
            p0 += __shfl_xor(p0, m);
            p1 += __shfl_xor(p1, m);
        }
        if (jg == 0) {
            out[(g * G + r) * N_CLS + 0] = p0 + clfb[0];
            out[(g * G + r) * N_CLS + 1] = p1 + clfb[1];
        }
    }
}

// ---------------------------------------------------------------------------
// Fallback (workspace too small for the 51.5 MB table): R11-style VALU path.
// ---------------------------------------------------------------------------
__global__ __launch_bounds__(512, 2)
void rnn_fallback_kernel(const int*   __restrict__ batch,
                         const float* __restrict__ emb,
                         const float* __restrict__ wxw,
                         const float* __restrict__ wxb,
                         const float* __restrict__ whw,
                         const float* __restrict__ whb,
                         const float* __restrict__ clfw,
                         const float* __restrict__ clfb,
                         float*       __restrict__ out)
{
    const int b    = blockIdx.x;
    const int tid  = threadIdx.x;
    const int j    = tid >> 1;
    const int half = tid & 1;
    const int k0   = half * 128;

    __shared__ float hbuf[2][HID];
    __shared__ float ebuf[2][D_EMB];

    float w[128];
#pragma unroll
    for (int k = 0; k < 128; ++k)
        w[k] = whw[(size_t)(k0 + k) * HID + j];

    float wx[64];
#pragma unroll
    for (int d = 0; d < 64; ++d)
        wx[d] = wxw[(size_t)(half * 64 + d) * HID + j];

    const float bj  = whb[j];
    const float axb = wxb[j];

    if (tid < HID) hbuf[0][tid] = 0.f;

    const int* brow = batch + (size_t)b * T_LEN;

    int tok_n = brow[0];
    if (tid < D_EMB) ebuf[0][tid] = emb[(size_t)tok_n * D_EMB + tid];
    tok_n = brow[1];
    __syncthreads();

    float h_j = 0.f;
    int cur = 0;
    for (int t = 0; t < T_LEN; ++t) {
        const int nxt = cur ^ 1;
        const int tok_nn = (t + 2 < T_LEN) ? brow[t + 2] : 0;
        float ev = 0.f;
        if (t + 1 < T_LEN && tid < D_EMB)
            ev = emb[(size_t)tok_n * D_EMB + tid];

        float a0 = 0.f, a1 = 0.f, a2 = 0.f, a3 = 0.f;
        const float4* hv = (const float4*)&hbuf[cur][k0];
#pragma unroll
        for (int i = 0; i < 32; ++i) {
            float4 h4 = hv[i];
            a0 = fmaf(h4.x, w[4 * i + 0], a0);
            a1 = fmaf(h4.y, w[4 * i + 1], a1);
            a2 = fmaf(h4.z, w[4 * i + 2], a2);
            a3 = fmaf(h4.w, w[4 * i + 3], a3);
        }
        const float4* evv = (const float4*)&ebuf[cur][half * 64];
#pragma unroll
        for (int i = 0; i < 16; ++i) {
            float4 e4 = evv[i];
            a0 = fmaf(e4.x, wx[4 * i + 0], a0);
            a1 = fmaf(e4.y, wx[4 * i + 1], a1);
            a2 = fmaf(e4.z, wx[4 * i + 2], a2);
            a3 = fmaf(e4.w, wx[4 * i + 3], a3);
        }
        float s = (a0 + a1) + (a2 + a3);
        s += __shfl_xor(s, 1);

        h_j = fast_tanh(s + bj + axb);

        if (half == 0) hbuf[nxt][j] = h_j;
        if (t + 1 < T_LEN && tid < D_EMB) ebuf[nxt][tid] = ev;
        __syncthreads();

        tok_n = tok_nn;
        cur   = nxt;
    }

    if (half == 0) {
        hbuf[0][j] = h_j * clfw[j * N_CLS + 0];
        hbuf[1][j] = h_j * clfw[j * N_CLS + 1];
    }
    __syncthreads();
    if (tid < 64) {
        float v = hbuf[0][tid] + hbuf[0][tid + 64] +
                  hbuf[0][tid + 128] + hbuf[0][tid + 192];
#pragma unroll
        for (int off = 32; off > 0; off >>= 1) v += __shfl_xor(v, off);
        if (tid == 0) out[b * N_CLS + 0] = v + clfb[0];
    } else if (tid < 128) {
        const int l = tid - 64;
        float v = hbuf[1][l] + hbuf[1][l + 64] +
                  hbuf[1][l + 128] + hbuf[1][l + 192];
#pragma unroll
        for (int off = 32; off > 0; off >>= 1) v += __shfl_xor(v, off);
        if (l == 0) out[b * N_CLS + 1] = v + clfb[1];
    }
}

// ---------------------------------------------------------------------------
extern "C" void kernel_launch(void* const* d_in, const int* in_sizes, int n_in,
                              void* d_out, int out_size, void* d_ws, size_t ws_size,
                              hipStream_t stream)
{
    const int*   batch = (const int*)  d_in[0];
    const float* emb   = (const float*)d_in[1];
    const float* wxw   = (const float*)d_in[2];
    const float* wxb   = (const float*)d_in[3];
    const float* whw   = (const float*)d_in[4];
    const float* whb   = (const float*)d_in[5];
    const float* clfw  = (const float*)d_in[6];
    const float* clfb  = (const float*)d_in[7];
    float* out = (float*)d_out;

    const size_t tab_bytes = (size_t)VOCAB * HID * sizeof(float);
    if (ws_size >= tab_bytes) {
        float* tab = (float*)d_ws;
        tabax_kernel<<<(VOCAB + 31) / 32, 256, 0, stream>>>(emb, wxw, wxb, whb, tab);
        rnn_mfma_kernel<<<NBLK, 256, 0, stream>>>(batch, whw, clfw, clfb, tab, out);
    } else {
        rnn_fallback_kernel<<<BSZ, 512, 0, stream>>>(batch, emb, wxw, wxb, whw, whb,
                                                     clfw, clfb, out);
    }
}

// Round 18
// 1366.631 us; speedup vs baseline: 3.6152x; 3.6152x over previous
//
#include <hip/hip_runtime.h>
#include <hip/hip_bf16.h>

// Problem constants (match reference).
#define VOCAB  50257
#define D_EMB  128
#define HID    256
#define N_CLS  2
#define BSZ    256
#define T_LEN  2048

// ---------------------------------------------------------------------------
// Kernel 1: tab[v][j] = sum_d emb_table[v][d] * wx_w[d][j] + wx_b[j] + wh_b[j]
// ---------------------------------------------------------------------------
__global__ __launch_bounds__(256)
void tabax_kernel(const float* __restrict__ emb,
                  const float* __restrict__ wxw,
                  const float* __restrict__ wxb,
                  const float* __restrict__ whb,
                  float* __restrict__ tab)
{
    const int j  = threadIdx.x;          // output unit 0..255
    const int v0 = blockIdx.x * 32;
    const int rows = min(32, VOCAB - v0);

    __shared__ float ebuf[32 * D_EMB];   // 16 KB
    for (int i = j; i < rows * D_EMB; i += 256)
        ebuf[i] = emb[(size_t)v0 * D_EMB + i];
    __syncthreads();

    float acc[32];
#pragma unroll
    for (int r = 0; r < 32; ++r) acc[r] = 0.f;

#pragma unroll 8
    for (int d = 0; d < D_EMB; ++d) {
        float wxv = wxw[d * HID + j];    // coalesced
#pragma unroll
        for (int r = 0; r < 32; ++r)
            acc[r] = fmaf(ebuf[r * D_EMB + d], wxv, acc[r]); // LDS broadcast
    }

    const float bb = wxb[j] + whb[j];
    for (int r = 0; r < rows; ++r)
        tab[(size_t)(v0 + r) * HID + j] = acc[r] + bb;       // coalesced
}

__device__ __forceinline__ float fast_tanh(float x) {
    float e2 = __expf(2.f * x);
    return 1.f - 2.f / (e2 + 1.f);
}

// Pure-VALU 16-lane reduction: DPP row_ror add (DPP rows of 16 = exactly our
// kg-groups). Replaces __shfl_xor (ds_swizzle on the DS pipe, lgkmcnt stalls)
// with single-cycle-issue VALU adds. acc = ror(acc, N) + acc per level;
// after levels 8,4,2,1 every lane in the row holds the full 16-lane sum.
#define DPP_RADD(ACC, N)                                                    \
    asm("v_add_f32 %0, %0, %0 row_ror:" #N " row_mask:0xf bank_mask:0xf"    \
        : "+v"(ACC))

// ---------------------------------------------------------------------------
// Kernel 2 (main): one block per batch row, 1024 threads (16 waves, 4/SIMD).
// Identical geometry to the 1556us R11 kernel: thread (cg = tid>>4,
// kg = tid&15) owns cols [cg*4, cg*4+4) over k in [kg*16, kg*16+16);
// W[4][4][4] = 64 f32, one-time pin; swizzled ds_read_b128 h reads
// (rot=(kg>>2)&3, 0 conflicts measured); x2 time unroll.
// ONE change: the k-reduce is now a DPP rotate-reduce (16 VALU adds, no DS
// ops, 4 independent chains) + 3 loop-invariant cndmask selects, instead of
// the shfl_xor sel-pair tree (5 ds_swizzle + 6 cndmask with serialized
// lgkmcnt waits). Writers are lanes kg<4 (consecutive cols c0+kg).
// ---------------------------------------------------------------------------
__global__ __launch_bounds__(1024, 1)
void rnn_main_kernel(const int*   __restrict__ batch,
                     const float* __restrict__ whw,
                     const float* __restrict__ clfw,
                     const float* __restrict__ clfb,
                     const float* __restrict__ ax_tab,
                     float*       __restrict__ out)
{
    const int b   = blockIdx.x;
    const int tid = threadIdx.x;
    const int kg  = tid & 15;            // k-group: k in [kg*16, kg*16+16)
    const int cg  = tid >> 4;            // col-group: cols [cg*4, cg*4+4)
    const int c0  = cg * 4;
    const int kb  = kg * 16;
    const int rot = (kg >> 2) & 3;       // bank-swizzle rotation
    const int q   = kg & 3;              // which of the 4 cols this lane picks

    __shared__ float hbuf[2][HID];       // double-buffered hidden state
    __shared__ float sbuf[2][HID];       // epilogue scratch

    // --- one-time weight load: W[e][m][i] = wh_w[kb+((e+rot)&3)*4+m][c0+i] ---
    float W[4][4][4];
#pragma unroll
    for (int e = 0; e < 4; ++e) {
        const int swz = (e + rot) & 3;
#pragma unroll
        for (int m = 0; m < 4; ++m) {
            const int k = kb + swz * 4 + m;
            const float4 w4 = *(const float4*)&whw[(size_t)k * HID + c0];
            W[e][m][0] = w4.x; W[e][m][1] = w4.y;
            W[e][m][2] = w4.z; W[e][m][3] = w4.w;
        }
    }
    // Pin once: asm redefines each value -> loads cannot be rematerialized.
#pragma unroll
    for (int e = 0; e < 4; ++e)
#pragma unroll
        for (int m = 0; m < 4; ++m)
            asm volatile("" : "+v"(W[e][m][0]), "+v"(W[e][m][1]),
                              "+v"(W[e][m][2]), "+v"(W[e][m][3]));

    // LDS byte offsets of the 4 swizzled float4 reads (within one h buffer).
    int lds_off[4];
#pragma unroll
    for (int e = 0; e < 4; ++e) lds_off[e] = kg * 64 + ((e + rot) & 3) * 16;

    const int  mycol = c0 + q;           // column this lane selects / writes
    const bool wr    = (kg < 4);         // lanes 0..3 of each row write

    if (tid < HID) hbuf[0][tid] = 0.f;

    const int* brow = batch + (size_t)b * T_LEN;
    const float* axp = ax_tab + mycol;   // 32-bit offsets: tok*256 elems
    int tok_n = brow[0];
    float axv = axp[(unsigned)tok_n * 256u];           // ax for t=0
    tok_n = brow[1];
    __syncthreads();

#define RNN_STEP(CUR, NXT, TT)                                              \
    {                                                                       \
        const int tok_nn = ((TT) + 2 < T_LEN) ? brow[(TT) + 2] : 0;         \
        const float ax_n = axp[(unsigned)tok_n * 256u];                     \
        float acc[4];                                                       \
        const char* hb = (const char*)&hbuf[CUR][0];                        \
        {   /* e = 0 initializes acc */                                     \
            const float4 h4 = *(const float4*)(hb + lds_off[0]);            \
            const float hm[4] = {h4.x, h4.y, h4.z, h4.w};                   \
            _Pragma("unroll")                                               \
            for (int i = 0; i < 4; ++i) acc[i] = hm[0] * W[0][0][i];        \
            _Pragma("unroll")                                               \
            for (int m = 1; m < 4; ++m)                                     \
                _Pragma("unroll")                                           \
                for (int i = 0; i < 4; ++i)                                 \
                    acc[i] = fmaf(hm[m], W[0][m][i], acc[i]);               \
        }                                                                   \
        _Pragma("unroll")                                                   \
        for (int e = 1; e < 4; ++e) {                                       \
            const float4 h4 = *(const float4*)(hb + lds_off[e]);            \
            const float hm[4] = {h4.x, h4.y, h4.z, h4.w};                   \
            _Pragma("unroll")                                               \
            for (int m = 0; m < 4; ++m)                                     \
                _Pragma("unroll")                                           \
                for (int i = 0; i < 4; ++i)                                 \
                    acc[i] = fmaf(hm[m], W[e][m][i], acc[i]);               \
        }                                                                   \
        /* DPP rotate-reduce over the 16-lane row: 4 independent chains */  \
        _Pragma("unroll")                                                   \
        for (int i = 0; i < 4; ++i) {                                       \
            DPP_RADD(acc[i], 8);                                            \
            DPP_RADD(acc[i], 4);                                            \
            DPP_RADD(acc[i], 2);                                            \
            DPP_RADD(acc[i], 1);                                            \
        }                                                                   \
        /* loop-invariant-mask selects: lane takes acc[q] */                \
        const float r01 = (q & 1) ? acc[1] : acc[0];                        \
        const float r23 = (q & 1) ? acc[3] : acc[2];                        \
        const float res = (q & 2) ? r23 : r01;                              \
        const float hnew = fast_tanh(res + axv);                            \
        if (wr) hbuf[NXT][mycol] = hnew;                                    \
        __syncthreads();                                                    \
        axv   = ax_n;                                                       \
        tok_n = tok_nn;                                                     \
    }

    for (int t = 0; t < T_LEN; t += 2) {
        RNN_STEP(0, 1, t)
        RNN_STEP(1, 0, t + 1)
    }
#undef RNN_STEP

    // --- epilogue: out[b][c] = sum_j h[j] * clf_w[j][c] + clf_b[c] ---
    // After an even number of steps the final h is in hbuf[0].
    if (tid < HID) {
        const float h = hbuf[0][tid];
        sbuf[0][tid] = h * clfw[tid * N_CLS + 0];
        sbuf[1][tid] = h * clfw[tid * N_CLS + 1];
    }
    __syncthreads();
    if (tid < 64) {
        float v = sbuf[0][tid] + sbuf[0][tid + 64] +
                  sbuf[0][tid + 128] + sbuf[0][tid + 192];
#pragma unroll
        for (int off = 32; off > 0; off >>= 1) v += __shfl_xor(v, off);
        if (tid == 0) out[b * N_CLS + 0] = v + clfb[0];
    } else if (tid < 128) {
        const int l = tid - 64;
        float v = sbuf[1][l] + sbuf[1][l + 64] +
                  sbuf[1][l + 128] + sbuf[1][l + 192];
#pragma unroll
        for (int off = 32; off > 0; off >>= 1) v += __shfl_xor(v, off);
        if (l == 0) out[b * N_CLS + 1] = v + clfb[1];
    }
}

// ---------------------------------------------------------------------------
// Fallback (workspace too small for the 51.5 MB table).
// ---------------------------------------------------------------------------
__global__ __launch_bounds__(512, 2)
void rnn_fallback_kernel(const int*   __restrict__ batch,
                         const float* __restrict__ emb,
                         const float* __restrict__ wxw,
                         const float* __restrict__ wxb,
                         const float* __restrict__ whw,
                         const float* __restrict__ whb,
                         const float* __restrict__ clfw,
                         const float* __restrict__ clfb,
                         float*       __restrict__ out)
{
    const int b    = blockIdx.x;
    const int tid  = threadIdx.x;
    const int j    = tid >> 1;
    const int half = tid & 1;
    const int k0   = half * 128;

    __shared__ float hbuf[2][HID];
    __shared__ float ebuf[2][D_EMB];

    float w[128];
#pragma unroll
    for (int k = 0; k < 128; ++k)
        w[k] = whw[(size_t)(k0 + k) * HID + j];

    float wx[64];
#pragma unroll
    for (int d = 0; d < 64; ++d)
        wx[d] = wxw[(size_t)(half * 64 + d) * HID + j];

    const float bj  = whb[j];
    const float axb = wxb[j];

    if (tid < HID) hbuf[0][tid] = 0.f;

    const int* brow = batch + (size_t)b * T_LEN;

    int tok_n = brow[0];
    if (tid < D_EMB) ebuf[0][tid] = emb[(size_t)tok_n * D_EMB + tid];
    tok_n = brow[1];
    __syncthreads();

    float h_j = 0.f;
    int cur = 0;
    for (int t = 0; t < T_LEN; ++t) {
        const int nxt = cur ^ 1;
        const int tok_nn = (t + 2 < T_LEN) ? brow[t + 2] : 0;
        float ev = 0.f;
        if (t + 1 < T_LEN && tid < D_EMB)
            ev = emb[(size_t)tok_n * D_EMB + tid];

        float a0 = 0.f, a1 = 0.f, a2 = 0.f, a3 = 0.f;
        const float4* hv = (const float4*)&hbuf[cur][k0];
#pragma unroll
        for (int i = 0; i < 32; ++i) {
            float4 h4 = hv[i];
            a0 = fmaf(h4.x, w[4 * i + 0], a0);
            a1 = fmaf(h4.y, w[4 * i + 1], a1);
            a2 = fmaf(h4.z, w[4 * i + 2], a2);
            a3 = fmaf(h4.w, w[4 * i + 3], a3);
        }
        const float4* evv = (const float4*)&ebuf[cur][half * 64];
#pragma unroll
        for (int i = 0; i < 16; ++i) {
            float4 e4 = evv[i];
            a0 = fmaf(e4.x, wx[4 * i + 0], a0);
            a1 = fmaf(e4.y, wx[4 * i + 1], a1);
            a2 = fmaf(e4.z, wx[4 * i + 2], a2);
            a3 = fmaf(e4.w, wx[4 * i + 3], a3);
        }
        float s = (a0 + a1) + (a2 + a3);
        s += __shfl_xor(s, 1);

        h_j = fast_tanh(s + bj + axb);

        if (half == 0) hbuf[nxt][j] = h_j;
        if (t + 1 < T_LEN && tid < D_EMB) ebuf[nxt][tid] = ev;
        __syncthreads();

        tok_n = tok_nn;
        cur   = nxt;
    }

    if (half == 0) {
        hbuf[0][j] = h_j * clfw[j * N_CLS + 0];
        hbuf[1][j] = h_j * clfw[j * N_CLS + 1];
    }
    __syncthreads();
    if (tid < 64) {
        float v = hbuf[0][tid] + hbuf[0][tid + 64] +
                  hbuf[0][tid + 128] + hbuf[0][tid + 192];
#pragma unroll
        for (int off = 32; off > 0; off >>= 1) v += __shfl_xor(v, off);
        if (tid == 0) out[b * N_CLS + 0] = v + clfb[0];
    } else if (tid < 128) {
        const int l = tid - 64;
        float v = hbuf[1][l] + hbuf[1][l + 64] +
                  hbuf[1][l + 128] + hbuf[1][l + 192];
#pragma unroll
        for (int off = 32; off > 0; off >>= 1) v += __shfl_xor(v, off);
        if (l == 0) out[b * N_CLS + 1] = v + clfb[1];
    }
}

// ---------------------------------------------------------------------------
extern "C" void kernel_launch(void* const* d_in, const int* in_sizes, int n_in,
                              void* d_out, int out_size, void* d_ws, size_t ws_size,
                              hipStream_t stream)
{
    const int*   batch = (const int*)  d_in[0];
    const float* emb   = (const float*)d_in[1];
    const float* wxw   = (const float*)d_in[2];
    const float* wxb   = (const float*)d_in[3];
    const float* whw   = (const float*)d_in[4];
    const float* whb   = (const float*)d_in[5];
    const float* clfw  = (const float*)d_in[6];
    const float* clfb  = (const float*)d_in[7];
    float* out = (float*)d_out;

    const size_t tab_bytes = (size_t)VOCAB * HID * sizeof(float);
    if (ws_size >= tab_bytes) {
        float* tab = (float*)d_ws;
        tabax_kernel<<<(VOCAB + 31) / 32, 256, 0, stream>>>(emb, wxw, wxb, whb, tab);
        rnn_main_kernel<<<BSZ, 1024, 0, stream>>>(batch, whw, clfw, clfb, tab, out);
    } else {
        rnn_fallback_kernel<<<BSZ, 512, 0, stream>>>(batch, emb, wxw, wxb, whw, whb,
                                                     clfw, clfb, out);
    }
}